// Round 1
// baseline (164.049 us; speedup 1.0000x reference)
//
#include <hip/hip_runtime.h>
#include <hip/hip_bf16.h>
#include <math.h>

// FFM: B=32768, n=512, f=30, k=40
// inter[b] = X[b]^T W X[b],  W = 0.5*(C - diag(C)), C symmetric
// out = sigmoid(X@w1 + b + inter)
//
// R6: barrier-free K-loop. W16 (512 KB) is L2-resident (steady-state FETCH ~0),
// so Bs LDS staging + 2 full-drain barriers per BK step were pure latency.
// B fragments now load straight from global (16 full cache lines / instr),
// K-loop fully unrolled, zero __syncthreads inside. As (64 KB, full-K bf16,
// XOR-swizzled) kept: X read once per block, converted once, reused 4x + epilogue.

#define N_FEAT 512
#define FK 1200
#define KDIM 40
#define B_ROWS 32768
#define BM 64

typedef __attribute__((ext_vector_type(8))) short short8;
typedef __attribute__((ext_vector_type(4))) float f32x4;

__device__ __forceinline__ unsigned short bf16_rne(float f) {
    union { float f; unsigned int u; } c; c.f = f;
    unsigned int u = c.u;
    u += 0x7fffu + ((u >> 16) & 1u);
    return (unsigned short)(u >> 16);
}

__device__ __forceinline__ float bf16_to_f(unsigned short h) {
    union { unsigned int u; float f; } c;
    c.u = ((unsigned int)h) << 16;
    return c.f;
}

// ---------------- Kernel 1: build W16 (512x512 bf16) ----------------
__global__ __launch_bounds__(256) void build_w16(const float* __restrict__ v,
                                                 const int* __restrict__ f2f,
                                                 unsigned short* __restrict__ W16) {
    const int j = blockIdx.x * 256 + threadIdx.x;
    const int i = blockIdx.y;
    const int fi = f2f[i];
    const int fj = f2f[j];
    const float4* a = (const float4*)(v + (size_t)i * FK + (size_t)fj * KDIM);
    const float4* c = (const float4*)(v + (size_t)j * FK + (size_t)fi * KDIM);
    float acc = 0.f;
#pragma unroll
    for (int q = 0; q < KDIM / 4; ++q) {
        float4 av = a[q], cv = c[q];
        acc = fmaf(av.x, cv.x, acc);
        acc = fmaf(av.y, cv.y, acc);
        acc = fmaf(av.z, cv.z, acc);
        acc = fmaf(av.w, cv.w, acc);
    }
    W16[(size_t)i * N_FEAT + j] = (i == j) ? (unsigned short)0 : bf16_rne(0.5f * acc);
}

// ---------------- Kernel 2: fused GEMM + quadratic-form epilogue ----------------
// grid: 512 blocks x 256 threads (4 waves). Wave w: wm=w&1 (32 rows), wn=w>>1 (64 cols).
// As[r][c-chunk q] holds global chunk q^(r&7)  (16B chunks, swizzle kills bank conflicts).
// B fragments: direct global loads from L2-hot W16. No K-loop barriers.
__global__ __launch_bounds__(256, 2) void ffm_fused(const float* __restrict__ X,
                                                    const unsigned short* __restrict__ W16,
                                                    const float* __restrict__ w1,
                                                    const float* __restrict__ bvec,
                                                    float* __restrict__ out) {
    __shared__ __align__(16) unsigned short As[BM * N_FEAT];  // 64 KB, full-K X tile
    __shared__ float part[2 * BM];                            // 512 B

    const int tid  = threadIdx.x;
    const int lane = tid & 63;
    const int wave = tid >> 6;
    const int wm = wave & 1;
    const int wn = wave >> 1;
    const int quad = lane >> 4;
    const int l16  = lane & 15;
    const int aswz = l16 & 7;

    const size_t row0 = (size_t)blockIdx.x * BM;

    // ---- Phase A: stage As = bf16(X[row0 : row0+64][0:512]), swizzled ----
    {
        const float4* X4 = (const float4*)(X + row0 * N_FEAT);
        for (int u = 0; u < 16; ++u) {
            const int g  = u * 256 + tid;
            const int r  = g >> 6;          // 0..63
            const int cc = g & 63;          // 16B chunk in row
            float4 f0 = X4[r * 128 + cc * 2];
            float4 f1 = X4[r * 128 + cc * 2 + 1];
            union { unsigned short us[8]; short8 v; } pk;
            pk.us[0] = bf16_rne(f0.x);
            pk.us[1] = bf16_rne(f0.y);
            pk.us[2] = bf16_rne(f0.z);
            pk.us[3] = bf16_rne(f0.w);
            pk.us[4] = bf16_rne(f1.x);
            pk.us[5] = bf16_rne(f1.y);
            pk.us[6] = bf16_rne(f1.z);
            pk.us[7] = bf16_rne(f1.w);
            *(short8*)(As + r * N_FEAT + ((cc ^ (r & 7)) << 3)) = pk.v;
        }
    }
    __syncthreads();   // As ready; no further barriers until reduction

    float rs[2][4];
#pragma unroll
    for (int mi = 0; mi < 2; ++mi)
#pragma unroll
        for (int reg = 0; reg < 4; ++reg) rs[mi][reg] = 0.f;

    for (int cb = 0; cb < 4; ++cb) {
        const int col0 = cb * 128;

        f32x4 acc[2][4];
#pragma unroll
        for (int mi = 0; mi < 2; ++mi)
#pragma unroll
            for (int ni = 0; ni < 4; ++ni)
                acc[mi][ni] = (f32x4){0.f, 0.f, 0.f, 0.f};

        // Per-ni base pointers: row (col0+br) of W16, this lane's quad k-slot.
        const unsigned short* pb[4];
#pragma unroll
        for (int ni = 0; ni < 4; ++ni)
            pb[ni] = W16 + (size_t)(col0 + wn * 64 + ni * 16 + l16) * N_FEAT + quad * 8;

#pragma unroll
        for (int kk = 0; kk < 16; ++kk) {          // K-slice of 32 per step
            short8 a[2], b[4];
#pragma unroll
            for (int ni = 0; ni < 4; ++ni)
                b[ni] = *(const short8*)(pb[ni] + kk * 32);   // 64B imm offsets
            const int kc = kk * 4 + quad;                     // global 16B-chunk idx
#pragma unroll
            for (int mi = 0; mi < 2; ++mi) {
                const int ar = wm * 32 + mi * 16 + l16;       // ar&7 == aswz
                a[mi] = *(const short8*)(As + ar * N_FEAT + ((kc ^ aswz) << 3));
            }
#pragma unroll
            for (int mi = 0; mi < 2; ++mi)
#pragma unroll
                for (int ni = 0; ni < 4; ++ni)
                    acc[mi][ni] = __builtin_amdgcn_mfma_f32_16x16x32_bf16(
                        a[mi], b[ni], acc[mi][ni], 0, 0, 0);
        }

        // Epilogue for this col-block: rs += x_hat * (y + w1), x_hat from As (swizzled).
        float w1v[4];
#pragma unroll
        for (int ni = 0; ni < 4; ++ni)
            w1v[ni] = w1[col0 + wn * 64 + ni * 16 + l16];
#pragma unroll
        for (int mi = 0; mi < 2; ++mi) {
#pragma unroll
            for (int ni = 0; ni < 4; ++ni) {
                const int gc = col0 + wn * 64 + ni * 16 + l16;   // elem idx in K
#pragma unroll
                for (int reg = 0; reg < 4; ++reg) {
                    const int row = wm * 32 + mi * 16 + quad * 4 + reg;
                    const int adr = row * N_FEAT + ((((gc >> 3) ^ (row & 7)) << 3) | (gc & 7));
                    const float xf = bf16_to_f(As[adr]);
                    rs[mi][reg] = fmaf(xf, acc[mi][ni][reg] + w1v[ni], rs[mi][reg]);
                }
            }
        }
    }

    // Reduce over l16, combine wn halves, bias + sigmoid.
#pragma unroll
    for (int mi = 0; mi < 2; ++mi)
#pragma unroll
        for (int reg = 0; reg < 4; ++reg) {
            float r = rs[mi][reg];
#pragma unroll
            for (int off = 1; off < 16; off <<= 1)
                r += __shfl_xor(r, off, 16);
            if (l16 == 0)
                part[wn * BM + wm * 32 + mi * 16 + quad * 4 + reg] = r;
        }
    __syncthreads();

    if (tid < BM) {
        const float t = part[tid] + part[BM + tid] + bvec[0];
        out[row0 + tid] = 1.0f / (1.0f + expf(-t));
    }
}

extern "C" void kernel_launch(void* const* d_in, const int* in_sizes, int n_in,
                              void* d_out, int out_size, void* d_ws, size_t ws_size,
                              hipStream_t stream) {
    const float* X   = (const float*)d_in[0];   // 32768 x 512
    const float* w1  = (const float*)d_in[1];   // 512
    const float* b   = (const float*)d_in[2];   // 1
    const float* v   = (const float*)d_in[3];   // 512 x 30 x 40
    const int*   f2f = (const int*)d_in[4];     // 512
    float* out = (float*)d_out;                 // 32768

    unsigned short* W16 = (unsigned short*)d_ws;   // 512 KB scratch

    build_w16<<<dim3(2, N_FEAT), 256, 0, stream>>>(v, f2f, W16);
    ffm_fused<<<B_ROWS / BM, 256, 0, stream>>>(X, W16, w1, b, out);
}

// Round 2
// 141.729 us; speedup vs baseline: 1.1575x; 1.1575x over previous
//
#include <hip/hip_runtime.h>
#include <hip/hip_bf16.h>
#include <math.h>

// FFM: B=32768, n=512, f=30, k=40
// inter[b] = X[b]^T W X[b],  W = 0.5*(C - diag(C)), C symmetric
// out = sigmoid(X@w1 + b + inter)
//
// R7: counted-vmcnt double-buffered pipeline (T3+T4). Bs[2] 16KB halves,
// 2 global_load_lds per thread per step, s_waitcnt vmcnt(2) (never 0 in
// loop), raw s_barrier only. 8 waves/block (512 thr), 97KB LDS -> 1
// block/CU = 2 waves/SIMD. Fully unrolled 32-step K-loop (static idx).
// As (64KB full-K X tile, XOR-swizzled) unchanged from R5.

#define N_FEAT 512
#define FK 1200
#define KDIM 40
#define B_ROWS 32768
#define BM 64
#define BK 64

typedef __attribute__((ext_vector_type(8))) short short8;
typedef __attribute__((ext_vector_type(4))) float f32x4;

__device__ __forceinline__ unsigned short bf16_rne(float f) {
    union { float f; unsigned int u; } c; c.f = f;
    unsigned int u = c.u;
    u += 0x7fffu + ((u >> 16) & 1u);
    return (unsigned short)(u >> 16);
}

__device__ __forceinline__ float bf16_to_f(unsigned short h) {
    union { unsigned int u; float f; } c;
    c.u = ((unsigned int)h) << 16;
    return c.f;
}

__device__ __forceinline__ void async_copy16(const void* g, void* l) {
    __builtin_amdgcn_global_load_lds(
        (const __attribute__((address_space(1))) void*)g,
        (__attribute__((address_space(3))) void*)l,
        16, 0, 0);
}

#define FENCE() asm volatile("" ::: "memory")

// ---------------- Kernel 1: build W16 (512x512 bf16) ----------------
__global__ __launch_bounds__(256) void build_w16(const float* __restrict__ v,
                                                 const int* __restrict__ f2f,
                                                 unsigned short* __restrict__ W16) {
    const int j = blockIdx.x * 256 + threadIdx.x;
    const int i = blockIdx.y;
    const int fi = f2f[i];
    const int fj = f2f[j];
    const float4* a = (const float4*)(v + (size_t)i * FK + (size_t)fj * KDIM);
    const float4* c = (const float4*)(v + (size_t)j * FK + (size_t)fi * KDIM);
    float acc = 0.f;
#pragma unroll
    for (int q = 0; q < KDIM / 4; ++q) {
        float4 av = a[q], cv = c[q];
        acc = fmaf(av.x, cv.x, acc);
        acc = fmaf(av.y, cv.y, acc);
        acc = fmaf(av.z, cv.z, acc);
        acc = fmaf(av.w, cv.w, acc);
    }
    W16[(size_t)i * N_FEAT + j] = (i == j) ? (unsigned short)0 : bf16_rne(0.5f * acc);
}

// ---------------- Kernel 2: fused GEMM + quadratic-form epilogue ----------------
// grid: 512 blocks x 512 threads (8 waves). Wave w: wm=w&1 (32 rows),
// wn=w>>1 (32 cols of the 128-col cb block). Per-wave output 32x32 / cb.
// Pipeline: per K-step issue stage(s+1) -> vmcnt(2) -> s_barrier -> MFMA
// from Bs[s&1] -> s_barrier. Staging loads for s+1 stay in flight across
// the whole compute phase.
__global__ __launch_bounds__(512, 2) void ffm_fused(const float* __restrict__ X,
                                                    const unsigned short* __restrict__ W16,
                                                    const float* __restrict__ w1,
                                                    const float* __restrict__ bvec,
                                                    float* __restrict__ out) {
    __shared__ __align__(16) unsigned short As[BM * N_FEAT];   // 64 KB, full-K X tile
    __shared__ __align__(16) unsigned short Bs[2][128 * BK];   // 2 x 16 KB, W16 dbuf
    __shared__ float part[4 * BM];                             // 1 KB

    const int tid  = threadIdx.x;
    const int lane = tid & 63;
    const int wave = tid >> 6;       // 0..7
    const int wm = wave & 1;
    const int wn = wave >> 1;        // 0..3
    const int quad = lane >> 4;
    const int l16  = lane & 15;
    const int aswz = l16 & 7;

    const size_t row0 = (size_t)blockIdx.x * BM;

    // Bs staging coords (XOR preimage so LDS dest stays lane-contiguous).
    const int srow = lane >> 3;                    // 0..7
    const int scol = (((lane & 7) ^ srow) << 3);   // element offset within BK row

    // Preload w1 fragments + bias: no VMEM ops inside the pipelined loop.
    float w1v[4][2];
#pragma unroll
    for (int cb = 0; cb < 4; ++cb)
#pragma unroll
        for (int ni = 0; ni < 2; ++ni)
            w1v[cb][ni] = w1[cb * 128 + wn * 32 + ni * 16 + l16];
    const float bias = bvec[0];

    // Stage 16KB W16 tile for step s into Bs[s&1]: 2 global_load_lds/thread.
    auto stage = [&](int s) {
        const int col0 = (s >> 3) * 128;
        const int k0   = (s & 7) * 64;
        unsigned short* dst = (unsigned short*)Bs[s & 1];
#pragma unroll
        for (int c = 0; c < 2; ++c) {
            const int chunk = wave * 2 + c;      // 0..15 (wave-uniform)
            const int r = chunk * 8 + srow;      // Bs row 0..127
            async_copy16(W16 + (size_t)(col0 + r) * N_FEAT + k0 + scol,
                         dst + chunk * 512);
        }
    };

    // ---- Prologue: issue tile-0 staging, then build As under it ----
    stage(0);
    {
        const float4* X4 = (const float4*)(X + row0 * N_FEAT);
#pragma unroll
        for (int u = 0; u < 8; ++u) {
            const int g  = u * 512 + tid;
            const int r  = g >> 6;          // 0..63
            const int cc = g & 63;          // 16B chunk in row
            float4 f0 = X4[r * 128 + cc * 2];
            float4 f1 = X4[r * 128 + cc * 2 + 1];
            union { unsigned short us[8]; short8 v; } pk;
            pk.us[0] = bf16_rne(f0.x);
            pk.us[1] = bf16_rne(f0.y);
            pk.us[2] = bf16_rne(f0.z);
            pk.us[3] = bf16_rne(f0.w);
            pk.us[4] = bf16_rne(f1.x);
            pk.us[5] = bf16_rne(f1.y);
            pk.us[6] = bf16_rne(f1.z);
            pk.us[7] = bf16_rne(f1.w);
            *(short8*)(As + r * N_FEAT + ((cc ^ (r & 7)) << 3)) = pk.v;
        }
    }
    // As ds_writes must be drained + all waves arrived before MFMA reads.
    asm volatile("s_waitcnt lgkmcnt(0)" ::: "memory");
    __builtin_amdgcn_s_barrier();
    FENCE();

    float rs[2][4];
#pragma unroll
    for (int mi = 0; mi < 2; ++mi)
#pragma unroll
        for (int reg = 0; reg < 4; ++reg) rs[mi][reg] = 0.f;

    f32x4 acc[2][2];
#pragma unroll
    for (int mi = 0; mi < 2; ++mi)
#pragma unroll
        for (int ni = 0; ni < 2; ++ni)
            acc[mi][ni] = (f32x4){0.f, 0.f, 0.f, 0.f};

#pragma unroll
    for (int cb = 0; cb < 4; ++cb) {
        const int col0 = cb * 128;
#pragma unroll
        for (int t = 0; t < 8; ++t) {
            const int s = cb * 8 + t;
            // Issue next tile's staging (overwrites buffer last read at s-1;
            // end-of-step barrier below makes that safe).
            if (s < 31) {
                stage(s + 1);
                asm volatile("s_waitcnt vmcnt(2)" ::: "memory");  // cur buf done, next in flight
            } else {
                asm volatile("s_waitcnt vmcnt(0)" ::: "memory");
            }
            __builtin_amdgcn_s_barrier();   // all waves' cur-buf loads complete
            FENCE();

            const unsigned short* bs = (const unsigned short*)Bs[s & 1];
            const int k0 = t * 64;
#pragma unroll
            for (int kk = 0; kk < 2; ++kk) {
                short8 a[2], b[2];
                const int kc = (k0 >> 3) + kk * 4 + quad;     // global 16B-chunk idx
#pragma unroll
                for (int mi = 0; mi < 2; ++mi) {
                    const int ar = wm * 32 + mi * 16 + l16;   // ar&7 == aswz
                    a[mi] = *(const short8*)(As + ar * N_FEAT + ((kc ^ aswz) << 3));
                }
                const int swc = ((kk * 4 + quad) ^ aswz) << 3;
#pragma unroll
                for (int ni = 0; ni < 2; ++ni) {
                    const int br = wn * 32 + ni * 16 + l16;   // br&7 == aswz
                    b[ni] = *(const short8*)(bs + br * BK + swc);
                }
#pragma unroll
                for (int mi = 0; mi < 2; ++mi)
#pragma unroll
                    for (int ni = 0; ni < 2; ++ni)
                        acc[mi][ni] = __builtin_amdgcn_mfma_f32_16x16x32_bf16(
                            a[mi], b[ni], acc[mi][ni], 0, 0, 0);
            }

            FENCE();
            __builtin_amdgcn_s_barrier();   // cur-buf reads done before overwrite at s+1
            FENCE();
        }

        // Epilogue for this col-block: rs += x_hat * (y + w1), x_hat from As.
#pragma unroll
        for (int mi = 0; mi < 2; ++mi) {
#pragma unroll
            for (int ni = 0; ni < 2; ++ni) {
                const int gc = col0 + wn * 32 + ni * 16 + l16;   // elem idx in K
#pragma unroll
                for (int reg = 0; reg < 4; ++reg) {
                    const int row = wm * 32 + mi * 16 + quad * 4 + reg;
                    const int adr = row * N_FEAT + ((((gc >> 3) ^ (row & 7)) << 3) | (gc & 7));
                    const float xf = bf16_to_f(As[adr]);
                    rs[mi][reg] = fmaf(xf, acc[mi][ni][reg] + w1v[cb][ni], rs[mi][reg]);
                }
                acc[mi][ni] = (f32x4){0.f, 0.f, 0.f, 0.f};
            }
        }
    }

    // Reduce over l16, combine the 4 wn column-quarters, bias + sigmoid.
#pragma unroll
    for (int mi = 0; mi < 2; ++mi)
#pragma unroll
        for (int reg = 0; reg < 4; ++reg) {
            float r = rs[mi][reg];
#pragma unroll
            for (int off = 1; off < 16; off <<= 1)
                r += __shfl_xor(r, off, 16);
            if (l16 == 0)
                part[wn * BM + wm * 32 + mi * 16 + quad * 4 + reg] = r;
        }
    __syncthreads();

    if (tid < BM) {
        const float t = part[tid] + part[BM + tid] + part[2 * BM + tid] +
                        part[3 * BM + tid] + bias;
        out[row0 + tid] = 1.0f / (1.0f + expf(-t));
    }
}

extern "C" void kernel_launch(void* const* d_in, const int* in_sizes, int n_in,
                              void* d_out, int out_size, void* d_ws, size_t ws_size,
                              hipStream_t stream) {
    const float* X   = (const float*)d_in[0];   // 32768 x 512
    const float* w1  = (const float*)d_in[1];   // 512
    const float* b   = (const float*)d_in[2];   // 1
    const float* v   = (const float*)d_in[3];   // 512 x 30 x 40
    const int*   f2f = (const int*)d_in[4];     // 512
    float* out = (float*)d_out;                 // 32768

    unsigned short* W16 = (unsigned short*)d_ws;   // 512 KB scratch

    build_w16<<<dim3(2, N_FEAT), 256, 0, stream>>>(v, f2f, W16);
    ffm_fused<<<B_ROWS / BM, 512, 0, stream>>>(X, W16, w1, b, out);
}